// Round 19
// baseline (390.583 us; speedup 1.0000x reference)
//
#include <hip/hip_runtime.h>
#include <math.h>

#define HID 256

typedef __attribute__((ext_vector_type(8))) short short8;
typedef __attribute__((ext_vector_type(4))) float floatx4;

__device__ __forceinline__ ushort bf16_rne(float x) {
    uint u = __float_as_uint(x);
    uint r = (u + 0x7FFFu + ((u >> 16) & 1u)) >> 16;
    return (ushort)r;
}
__device__ __forceinline__ float bf16_to_f(ushort h) {
    return __uint_as_float(((uint)h) << 16);
}

// ---------- edge weight MLP; ONE packed uint64 atomic: high24=count, low40=deg*2^20
__global__ void k_edge(const int* __restrict__ eid, const int* __restrict__ epos,
                       const float* __restrict__ id_emb, const float* __restrict__ pos_emb,
                       const float* __restrict__ w1, const float* __restrict__ b1,
                       const float* __restrict__ w2, const float* __restrict__ b2,
                       const int* __restrict__ ei, float* __restrict__ ew,
                       unsigned long long* __restrict__ cnt64, int E) {
    __shared__ float sW1[100];
    __shared__ float sB1[10];
    __shared__ float sW2[10];
    __shared__ float sB2;
    int t = threadIdx.x;
    if (t < 100) sW1[t] = w1[t];
    if (t < 10) { sB1[t] = b1[t]; sW2[t] = w2[t]; }
    if (t == 0) sB2 = b2[0];
    __syncthreads();
    int e = blockIdx.x * blockDim.x + t;
    if (e >= E) return;
    int id = eid[e];
    int p  = epos[e];
    const float4* ide = (const float4*)(id_emb + (size_t)id * 8);
    float4 fa = ide[0], fb = ide[1];
    float f[10];
    f[0] = fa.x; f[1] = fa.y; f[2] = fa.z; f[3] = fa.w;
    f[4] = fb.x; f[5] = fb.y; f[6] = fb.z; f[7] = fb.w;
    f[8] = pos_emb[p * 2 + 0];
    f[9] = pos_emb[p * 2 + 1];
    float acc = sB2;
#pragma unroll
    for (int j = 0; j < 10; j++) {
        float h = sB1[j];
#pragma unroll
        for (int i = 0; i < 10; i++) h += f[i] * sW1[i * 10 + j];
        h = fmaxf(h, 0.f);
        acc += h * sW2[j];
    }
    float w = 1.f / (1.f + expf(-acc));
    ew[e] = w;
    int dst = ei[E + e];
    unsigned long long pack = (1ull << 40) + (unsigned long long)(w * 1048576.0f + 0.5f);
    atomicAdd(&cnt64[dst], pack);
}

// ---------- scan phase a (+dinv from cnt64 + nf4 pack + gsum zero + wprep blocks 0..63)
__global__ void k_scan_a(const unsigned long long* __restrict__ cnt64,
                         int* __restrict__ row_ptr, int* __restrict__ bsums,
                         float* __restrict__ deg, const float* __restrict__ nf,
                         float4* __restrict__ nf4, float* __restrict__ gsum,
                         const float* __restrict__ w2, const float* __restrict__ aw1,
                         ushort* __restrict__ w2h, ushort* __restrict__ w2l,
                         ushort* __restrict__ a1h, ushort* __restrict__ a1l, int N) {
    __shared__ int s[256];
    int b = blockIdx.x, t = threadIdx.x;
    int i = b * 256 + t;
    if (b == 0) gsum[t] = 0.f;
    if (b < 64) {  // wprep: Frag[c][t][L][j] = W[32c+(L>>4)*8+j][16t+(L&15)]
        int gid = b * 256 + t;
        int mat = gid >> 13;
        int rem = gid & 8191;
        int c = rem >> 10;
        int tt = (rem >> 6) & 15;
        int L = rem & 63;
        int k0 = 32 * c + (L >> 4) * 8;
        int n  = 16 * tt + (L & 15);
        const float* W = mat ? aw1 : w2;
        ushort* H  = mat ? a1h : w2h;
        ushort* Lo = mat ? a1l : w2l;
        short8 hv, lv;
#pragma unroll
        for (int j = 0; j < 8; j++) {
            float x = W[(size_t)(k0 + j) * HID + n];
            ushort h = bf16_rne(x);
            hv[j] = (short)h;
            lv[j] = (short)bf16_rne(x - bf16_to_f(h));
        }
        size_t off = (size_t)rem * 8;
        *(short8*)(H + off) = hv;
        *(short8*)(Lo + off) = lv;
    }
    int v = 0;
    if (i < N) {
        unsigned long long cv = cnt64[i];
        v = (int)(cv >> 40);
        float degf = (float)(cv & 0xFFFFFFFFFFull) * (1.0f / 1048576.0f);
        deg[i] = 1.f / sqrtf(degf + 1.f);
        nf4[i] = make_float4(nf[i * 3 + 0], nf[i * 3 + 1], nf[i * 3 + 2], 0.f);
    }
    s[t] = v;
    __syncthreads();
    for (int off = 1; off < 256; off <<= 1) {
        int u = (t >= off) ? s[t - off] : 0;
        __syncthreads();
        s[t] += u;
        __syncthreads();
    }
    int incl = s[t];
    if (i < N) row_ptr[i] = incl - v;
    if (t == 255) bsums[b] = incl;
}

// ---------- scan phase c: per-block offset from bsums prefix; copy to cursor
__global__ void k_scan_c(int* __restrict__ row_ptr, int* __restrict__ cursor,
                         const int* __restrict__ bsums, int N, int NB) {
    __shared__ int s[256];
    int b = blockIdx.x, t = threadIdx.x;
    int v = (t < NB) ? bsums[t] : 0;
    s[t] = (t < b) ? v : 0;
    __syncthreads();
    for (int off = 128; off > 0; off >>= 1) {
        if (t < off) s[t] += s[t + off];
        __syncthreads();
    }
    int boff = s[0];
    int i = b * 256 + t;
    if (i < N) {
        int rp = row_ptr[i] + boff;
        row_ptr[i] = rp;
        cursor[i] = rp;
    }
    if (b == NB - 1) {
        __syncthreads();
        s[t] = (t < NB) ? bsums[t] : 0;
        __syncthreads();
        for (int off = 128; off > 0; off >>= 1) {
            if (t < off) s[t] += s[t + off];
            __syncthreads();
        }
        if (t == 0) row_ptr[N] = s[0];
    }
}

// ---------- fill CSR, 2 edges/thread (two coalesced halves, independent atomic chains)
__global__ void k_fill(const int* __restrict__ ei, const float* __restrict__ ew,
                       const float* __restrict__ dinv, int* __restrict__ cursor,
                       int2* __restrict__ csr, int E, int Eh) {
    int g = blockIdx.x * blockDim.x + threadIdx.x;
    if (g < Eh) {
        int src = ei[g];
        int dst = ei[E + g];
        float norm = dinv[src] * ew[g] * dinv[dst];
        int slot = atomicAdd(&cursor[dst], 1);
        csr[slot] = make_int2(src, __float_as_int(norm));
    }
    int e2 = g + Eh;
    if (e2 < E) {
        int src = ei[e2];
        int dst = ei[E + e2];
        float norm = dinv[src] * ew[e2] * dinv[dst];
        int slot = atomicAdd(&cursor[dst], 1);
        csr[slot] = make_int2(src, __float_as_int(norm));
    }
}

// ---------- layer-1 aggregation, 8-wide batched loads
__global__ void k_agg3(const int* __restrict__ row_ptr, const int2* __restrict__ csr,
                       const float4* __restrict__ nf4, const float* __restrict__ dinv,
                       float4* __restrict__ T3, int N) {
    int n = blockIdx.x * blockDim.x + threadIdx.x;
    if (n >= N) return;
    int s = row_ptr[n];
    int e = row_ptr[n + 1];
    float ax = 0.f, ay = 0.f, az = 0.f;
    int i = s;
    for (; i + 8 <= e; i += 8) {
        int2 c[8];
        float4 t[8];
#pragma unroll
        for (int j = 0; j < 8; j++) c[j] = csr[i + j];
#pragma unroll
        for (int j = 0; j < 8; j++) t[j] = nf4[c[j].x];
#pragma unroll
        for (int j = 0; j < 8; j++) {
            float w = __int_as_float(c[j].y);
            ax = fmaf(w, t[j].x, ax);
            ay = fmaf(w, t[j].y, ay);
            az = fmaf(w, t[j].z, az);
        }
    }
    for (; i < e; i++) {
        int2 sn = csr[i];
        float w = __int_as_float(sn.y);
        float4 v = nf4[sn.x];
        ax = fmaf(w, v.x, ax);
        ay = fmaf(w, v.y, ay);
        az = fmaf(w, v.z, az);
    }
    float d = dinv[n];
    float dd = d * d;
    float4 v = nf4[n];
    ax = fmaf(dd, v.x, ax);
    ay = fmaf(dd, v.y, ay);
    az = fmaf(dd, v.z, az);
    T3[n] = make_float4(ax, ay, az, 0.f);
}

// ---------- per-edge x1-recompute + accumulate helper
__device__ __forceinline__ void gf_edge(float4 t, float wgt,
                                        const float4& w0, const float4& w1,
                                        const float4& w2, const float4& bv, float4& acc) {
    float xx = fmaxf(fmaf(t.x, w0.x, fmaf(t.y, w1.x, fmaf(t.z, w2.x, bv.x))), 0.f);
    float xy = fmaxf(fmaf(t.x, w0.y, fmaf(t.y, w1.y, fmaf(t.z, w2.y, bv.y))), 0.f);
    float xz = fmaxf(fmaf(t.x, w0.z, fmaf(t.y, w1.z, fmaf(t.z, w2.z, bv.z))), 0.f);
    float xw = fmaxf(fmaf(t.x, w0.w, fmaf(t.y, w1.w, fmaf(t.z, w2.w, bv.w))), 0.f);
    acc.x = fmaf(wgt, xx, acc.x);
    acc.y = fmaf(wgt, xy, acc.y);
    acc.z = fmaf(wgt, xz, acc.z);
    acc.w = fmaf(wgt, xw, acc.w);
}

// ---------- fused layer-2 aggregation, 8-wide batched loads; writes A as bf16 hi/lo
__global__ void k_gatherfused(const int* __restrict__ row_ptr, const int2* __restrict__ csr,
                              const float4* __restrict__ T3, const float* __restrict__ dinv,
                              const float* __restrict__ cw, const float* __restrict__ cb,
                              ushort* __restrict__ Ah, ushort* __restrict__ Al, int N) {
    int lane = threadIdx.x & 63;
    int wv = threadIdx.x >> 6;
    int n = blockIdx.x * 4 + wv;
    if (n >= N) return;
    const float4 w0 = *(const float4*)(cw + 4 * lane);
    const float4 w1 = *(const float4*)(cw + HID + 4 * lane);
    const float4 w2 = *(const float4*)(cw + 2 * HID + 4 * lane);
    const float4 bv = *(const float4*)(cb + 4 * lane);
    int s = row_ptr[n];
    int e = row_ptr[n + 1];
    float4 acc = make_float4(0.f, 0.f, 0.f, 0.f);
    int i = s;
    for (; i + 8 <= e; i += 8) {
        int2 c[8];
        float4 t[8];
#pragma unroll
        for (int j = 0; j < 8; j++) c[j] = csr[i + j];
#pragma unroll
        for (int j = 0; j < 8; j++) t[j] = T3[c[j].x];
#pragma unroll
        for (int j = 0; j < 8; j++)
            gf_edge(t[j], __int_as_float(c[j].y), w0, w1, w2, bv, acc);
    }
    for (; i < e; i++) {
        int2 sn = csr[i];
        gf_edge(T3[sn.x], __int_as_float(sn.y), w0, w1, w2, bv, acc);
    }
    float d = dinv[n];
    gf_edge(T3[n], d * d, w0, w1, w2, bv, acc);
    ushort4 hv, lv;
    ushort h;
    h = bf16_rne(acc.x); hv.x = h; lv.x = bf16_rne(acc.x - bf16_to_f(h));
    h = bf16_rne(acc.y); hv.y = h; lv.y = bf16_rne(acc.y - bf16_to_f(h));
    h = bf16_rne(acc.z); hv.z = h; lv.z = bf16_rne(acc.z - bf16_to_f(h));
    h = bf16_rne(acc.w); hv.w = h; lv.w = bf16_rne(acc.w - bf16_to_f(h));
    size_t base = (size_t)n * HID + lane * 4;
    *(ushort4*)(Ah + base) = hv;
    *(ushort4*)(Al + base) = lv;
}

// ================= MFMA double GEMM, 48-row tile (3 m-subtiles), 3 blocks/CU
#define ASTRIDE 264
#define MT 3
#define TROWS 48

__global__ __launch_bounds__(256, 3) void k_gemm_mfma(
        const ushort* __restrict__ Ah, const ushort* __restrict__ Al,
        const float* __restrict__ b2,
        const ushort* __restrict__ w2h, const ushort* __restrict__ w2l,
        const ushort* __restrict__ a1h, const ushort* __restrict__ a1l,
        float* __restrict__ P, float* __restrict__ gsum, int N) {
    __shared__ ushort Hs[TROWS * ASTRIDE];
    __shared__ ushort Ls[TROWS * ASTRIDE];
    int tid = threadIdx.x;
    int n0 = blockIdx.x * TROWS;
    int w = tid >> 6;
    int L = tid & 63;
    int quad = L >> 4, ln = L & 15;

    int arow[MT];
#pragma unroll
    for (int mt = 0; mt < MT; mt++) {
        int r = n0 + mt * 16 + ln;
        arow[mt] = (r < N) ? r : (N - 1);
    }

    floatx4 acc[4][MT];
#pragma unroll
    for (int i = 0; i < 4; i++)
#pragma unroll
        for (int j = 0; j < MT; j++) acc[i][j] = 0.f;
    {
        short8 pah[2][MT], pal[2][MT], pbh[2][4], pbl[2][4];
#pragma unroll
        for (int mt = 0; mt < MT; mt++) {
            size_t ab = (size_t)arow[mt] * HID + quad * 8;
            pah[0][mt] = *(const short8*)(Ah + ab);
            pal[0][mt] = *(const short8*)(Al + ab);
        }
#pragma unroll
        for (int nt = 0; nt < 4; nt++) {
            size_t off = ((size_t)(4 * w + nt) * 64 + L) * 8;
            pbh[0][nt] = *(const short8*)(w2h + off);
            pbl[0][nt] = *(const short8*)(w2l + off);
        }
#pragma unroll
        for (int c = 0; c < 8; c++) {
            int cur = c & 1, nxt = cur ^ 1;
            if (c < 7) {
#pragma unroll
                for (int mt = 0; mt < MT; mt++) {
                    size_t ab = (size_t)arow[mt] * HID + 32 * (c + 1) + quad * 8;
                    pah[nxt][mt] = *(const short8*)(Ah + ab);
                    pal[nxt][mt] = *(const short8*)(Al + ab);
                }
#pragma unroll
                for (int nt = 0; nt < 4; nt++) {
                    size_t off = ((size_t)((c + 1) * 16 + 4 * w + nt) * 64 + L) * 8;
                    pbh[nxt][nt] = *(const short8*)(w2h + off);
                    pbl[nxt][nt] = *(const short8*)(w2l + off);
                }
            }
#pragma unroll
            for (int nt = 0; nt < 4; nt++) {
#pragma unroll
                for (int mt = 0; mt < MT; mt++) {
                    acc[nt][mt] = __builtin_amdgcn_mfma_f32_16x16x32_bf16(pah[cur][mt], pbh[cur][nt], acc[nt][mt], 0, 0, 0);
                    acc[nt][mt] = __builtin_amdgcn_mfma_f32_16x16x32_bf16(pah[cur][mt], pbl[cur][nt], acc[nt][mt], 0, 0, 0);
                    acc[nt][mt] = __builtin_amdgcn_mfma_f32_16x16x32_bf16(pal[cur][mt], pbh[cur][nt], acc[nt][mt], 0, 0, 0);
                }
            }
        }
    }

#pragma unroll
    for (int nt = 0; nt < 4; nt++) {
        int col = (4 * w + nt) * 16 + ln;
        float bb = b2[col];
        float s = 0.f;
#pragma unroll
        for (int mt = 0; mt < MT; mt++) {
#pragma unroll
            for (int r = 0; r < 4; r++) {
                int row = n0 + mt * 16 + quad * 4 + r;
                float v = fmaxf(acc[nt][mt][r] + bb, 0.f);
                acc[nt][mt][r] = v;
                if (row < N) s += v;
            }
        }
        s += __shfl_down(s, 32, 64);
        s += __shfl_down(s, 16, 64);
        if (L < 16) atomicAdd(&gsum[col], s);
    }

#pragma unroll
    for (int nt = 0; nt < 4; nt++) {
        int col = (4 * w + nt) * 16 + ln;
#pragma unroll
        for (int mt = 0; mt < MT; mt++) {
#pragma unroll
            for (int r = 0; r < 4; r++) {
                int row = mt * 16 + quad * 4 + r;
                float v = acc[nt][mt][r];
                ushort h = bf16_rne(v);
                Hs[row * ASTRIDE + col] = h;
                Ls[row * ASTRIDE + col] = bf16_rne(v - bf16_to_f(h));
            }
        }
    }
    __syncthreads();

    floatx4 acc2[4][MT];
#pragma unroll
    for (int i = 0; i < 4; i++)
#pragma unroll
        for (int j = 0; j < MT; j++) acc2[i][j] = 0.f;
    {
        short8 pbh[2][4], pbl[2][4];
#pragma unroll
        for (int nt = 0; nt < 4; nt++) {
            size_t off = ((size_t)(4 * w + nt) * 64 + L) * 8;
            pbh[0][nt] = *(const short8*)(a1h + off);
            pbl[0][nt] = *(const short8*)(a1l + off);
        }
#pragma unroll
        for (int c = 0; c < 8; c++) {
            int cur = c & 1, nxt = cur ^ 1;
            if (c < 7) {
#pragma unroll
                for (int nt = 0; nt < 4; nt++) {
                    size_t off = ((size_t)((c + 1) * 16 + 4 * w + nt) * 64 + L) * 8;
                    pbh[nxt][nt] = *(const short8*)(a1h + off);
                    pbl[nxt][nt] = *(const short8*)(a1l + off);
                }
            }
            short8 ahf[MT], alf[MT];
#pragma unroll
            for (int mt = 0; mt < MT; mt++) {
                int base = (mt * 16 + ln) * ASTRIDE + 32 * c + quad * 8;
                ahf[mt] = *(const short8*)&Hs[base];
                alf[mt] = *(const short8*)&Ls[base];
            }
#pragma unroll
            for (int nt = 0; nt < 4; nt++) {
#pragma unroll
                for (int mt = 0; mt < MT; mt++) {
                    acc2[nt][mt] = __builtin_amdgcn_mfma_f32_16x16x32_bf16(ahf[mt], pbh[cur][nt], acc2[nt][mt], 0, 0, 0);
                    acc2[nt][mt] = __builtin_amdgcn_mfma_f32_16x16x32_bf16(ahf[mt], pbl[cur][nt], acc2[nt][mt], 0, 0, 0);
                    acc2[nt][mt] = __builtin_amdgcn_mfma_f32_16x16x32_bf16(alf[mt], pbh[cur][nt], acc2[nt][mt], 0, 0, 0);
                }
            }
        }
    }

#pragma unroll
    for (int nt = 0; nt < 4; nt++) {
        int col = (4 * w + nt) * 16 + ln;
#pragma unroll
        for (int mt = 0; mt < MT; mt++) {
#pragma unroll
            for (int r = 0; r < 4; r++) {
                int row = n0 + mt * 16 + quad * 4 + r;
                if (row < N) P[(size_t)row * HID + col] = acc2[nt][mt][r];
            }
        }
    }
}

// ---------- heads A (12 blocks): b<8 -> c1 slice; b>=8 -> gbias slice
__global__ void k_headsA(const float* __restrict__ gsum,
                         const float* __restrict__ cw1, const float* __restrict__ cb1,
                         float* __restrict__ c1g,
                         const float* __restrict__ aw1, const float* __restrict__ ab1,
                         float* __restrict__ gbias,
                         const float* __restrict__ cb3, float* __restrict__ sv_out,
                         float invN) {
    __shared__ float part[4][64];
    int b = blockIdx.x, t = threadIdx.x;
    int c = t & 63;
    int kr = t >> 6;
    if (b == 0 && t == 0) sv_out[0] = cb3[0];
    if (b < 8) {
        int col = b * 64 + c;
        float s = 0.f;
        for (int k = kr * 128; k < kr * 128 + 128; k++)
            s += gsum[k & (HID - 1)] * invN * cw1[(size_t)k * 512 + col];
        part[kr][c] = s;
        __syncthreads();
        if (kr == 0) {
            float v = cb1[col] + part[0][c] + part[1][c] + part[2][c] + part[3][c];
            c1g[col] = fmaxf(v, 0.f);
        }
    } else {
        int col = (b - 8) * 64 + c;
        float s = 0.f;
        for (int k = kr * 64; k < kr * 64 + 64; k++)
            s += gsum[k] * invN * aw1[(size_t)(HID + k) * HID + col];
        part[kr][c] = s;
        __syncthreads();
        if (kr == 0)
            gbias[col] = ab1[col] + part[0][c] + part[1][c] + part[2][c] + part[3][c];
    }
}

// ---------- merged heads B + logits: blocks 0..3 -> critic c2 slice; blocks 4.. -> logits
__global__ void k_headsBL(const float* __restrict__ c1g,
                          const float* __restrict__ cw2, const float* __restrict__ cb2,
                          const float* __restrict__ cw3, float* __restrict__ sv_out,
                          const float* __restrict__ P, const float* __restrict__ gbias,
                          const float* __restrict__ aw2, const float* __restrict__ ab2,
                          float* __restrict__ out, int N) {
    int b = blockIdx.x, t = threadIdx.x;
    if (b < 4) {
        __shared__ float part[4][64];
        int c = t & 63;
        int kr = t >> 6;
        int col = b * 64 + c;
        float s = 0.f;
        for (int k = kr * 128; k < kr * 128 + 128; k++)
            s += c1g[k] * cw2[(size_t)k * HID + col];
        part[kr][c] = s;
        __syncthreads();
        if (kr == 0) {
            float v = fmaxf(cb2[col] + part[0][c] + part[1][c] + part[2][c] + part[3][c], 0.f)
                    * cw3[col];
#pragma unroll
            for (int off = 32; off > 0; off >>= 1) v += __shfl_down(v, off, 64);
            if (c == 0) atomicAdd(sv_out, v);
        }
        return;
    }
    int lane = t & 63;
    int wv = t >> 6;
    int n = (b - 4) * 4 + wv;
    if (n >= N) return;
    float4 p = *(const float4*)(P + (size_t)n * HID + 4 * lane);
    float4 gb = *(const float4*)(gbias + 4 * lane);
    float4 w2 = *(const float4*)(aw2 + 4 * lane);
    float v = fmaxf(p.x + gb.x, 0.f) * w2.x
            + fmaxf(p.y + gb.y, 0.f) * w2.y
            + fmaxf(p.z + gb.z, 0.f) * w2.z
            + fmaxf(p.w + gb.w, 0.f) * w2.w;
#pragma unroll
    for (int off = 32; off > 0; off >>= 1) v += __shfl_down(v, off, 64);
    if (lane == 0) out[n] = v + ab2[0];
}

extern "C" void kernel_launch(void* const* d_in, const int* in_sizes, int n_in,
                              void* d_out, int out_size, void* d_ws, size_t ws_size,
                              hipStream_t stream) {
    const float* nf      = (const float*)d_in[0];
    const int*   ei      = (const int*)d_in[1];
    const int*   eid     = (const int*)d_in[2];
    const int*   epos    = (const int*)d_in[3];
    const float* id_emb  = (const float*)d_in[4];
    const float* pos_emb = (const float*)d_in[5];
    const float* ew_w1   = (const float*)d_in[6];
    const float* ew_b1   = (const float*)d_in[7];
    const float* ew_w2   = (const float*)d_in[8];
    const float* ew_b2   = (const float*)d_in[9];
    const float* c1w     = (const float*)d_in[10];
    const float* c1b     = (const float*)d_in[11];
    const float* c2w     = (const float*)d_in[12];
    const float* c2b     = (const float*)d_in[13];
    const float* aw1     = (const float*)d_in[14];
    const float* ab1     = (const float*)d_in[15];
    const float* aw2     = (const float*)d_in[16];
    const float* ab2     = (const float*)d_in[17];
    const float* cw1     = (const float*)d_in[18];
    const float* cb1     = (const float*)d_in[19];
    const float* cw2     = (const float*)d_in[20];
    const float* cb2     = (const float*)d_in[21];
    const float* cw3     = (const float*)d_in[22];
    const float* cb3     = (const float*)d_in[23];

    int N = in_sizes[0] / 3;
    int E = in_sizes[2];
    int NB = (N + 255) / 256;
    int Eh = (E + 1) / 2;
    float invN = 1.f / (float)N;

    char* ws = (char*)d_ws;
    unsigned long long* cnt64 = (unsigned long long*)ws;  ws += (size_t)N * 8;
    float* gsum     = (float*)ws;                         ws += HID * 4;
    float* deg      = (float*)ws;                         ws += (size_t)N * 4;
    ushort* Ah      = (ushort*)ws;                        ws += (size_t)N * HID * 2;
    ushort* Al      = (ushort*)ws;                        ws += (size_t)N * HID * 2;
    float* P        = (float*)ws;                         ws += (size_t)N * HID * 4;
    float* ew       = (float*)ws;                         ws += (size_t)E * 4;
    int2*  csr      = (int2*)ws;                          ws += (size_t)E * 8;
    int*   row_ptr  = (int*)ws;                           ws += (size_t)(N + 1) * 4;
    int*   cursor   = (int*)ws;                           ws += (size_t)N * 4;
    int*   bsums    = (int*)ws;                           ws += 256 * 4;
    float4* T3      = (float4*)ws;                        ws += (size_t)N * 16;
    float4* nf4     = (float4*)ws;                        ws += (size_t)N * 16;
    float* gbias    = (float*)ws;                         ws += HID * 4;
    float* c1g      = (float*)ws;                         ws += 512 * 4;
    ushort* w2h     = (ushort*)ws;                        ws += 65536 * 2;
    ushort* w2l     = (ushort*)ws;                        ws += 65536 * 2;
    ushort* a1h     = (ushort*)ws;                        ws += 65536 * 2;
    ushort* a1l     = (ushort*)ws;                        ws += 65536 * 2;

    float* out = (float*)d_out;  // [N] logits + [1] state value

    // --- zero cnt64 (gsum zeroed in k_scan_a)
    hipMemsetAsync(cnt64, 0, (size_t)N * 8, stream);

    // --- edge MLP + packed degree/count atomic
    k_edge<<<(E + 255) / 256, 256, 0, stream>>>(eid, epos, id_emb, pos_emb,
                                                ew_w1, ew_b1, ew_w2, ew_b2, ei, ew, cnt64, E);

    // --- scan a (+ dinv + nf4 pack + gsum zero + wprep), then c
    k_scan_a<<<NB, 256, 0, stream>>>(cnt64, row_ptr, bsums, deg, nf, nf4, gsum,
                                     c2w, aw1, w2h, w2l, a1h, a1l, N);
    k_scan_c<<<NB, 256, 0, stream>>>(row_ptr, cursor, bsums, N, NB);

    // --- fill CSR (2 edges/thread)
    k_fill<<<(Eh + 255) / 256, 256, 0, stream>>>(ei, ew, deg, cursor, csr, E, Eh);

    // --- layer 1 aggregate on raw features (8-wide batched)
    k_agg3<<<(N + 255) / 256, 256, 0, stream>>>(row_ptr, csr, nf4, deg, T3, N);

    // --- layer 2 aggregate (8-wide batched); writes A as bf16 hi/lo
    k_gatherfused<<<(N + 3) / 4, 256, 0, stream>>>(row_ptr, csr, T3, deg, c1w, c1b, Ah, Al, N);

    // --- MFMA fused conv2-GEMM + actor-GEMM (+ colsum); 48-row tiles, 3 blocks/CU
    k_gemm_mfma<<<(N + TROWS - 1) / TROWS, 256, 0, stream>>>(Ah, Al, c2b, w2h, w2l,
                                                             a1h, a1l, P, gsum, N);

    // --- heads A (c1 + gbias), then merged heads B + logits
    k_headsA<<<12, 256, 0, stream>>>(gsum, cw1, cb1, c1g, aw1, ab1, gbias,
                                     cb3, out + N, invN);
    k_headsBL<<<4 + (N + 3) / 4, 256, 0, stream>>>(c1g, cw2, cb2, cw3, out + N,
                                                   P, gbias, aw2, ab2, out, N);
}

// Round 20
// 375.714 us; speedup vs baseline: 1.0396x; 1.0396x over previous
//
#include <hip/hip_runtime.h>
#include <math.h>

#define HID 256

typedef __attribute__((ext_vector_type(8))) short short8;
typedef __attribute__((ext_vector_type(4))) float floatx4;

__device__ __forceinline__ ushort bf16_rne(float x) {
    uint u = __float_as_uint(x);
    uint r = (u + 0x7FFFu + ((u >> 16) & 1u)) >> 16;
    return (ushort)r;
}
__device__ __forceinline__ float bf16_to_f(ushort h) {
    return __uint_as_float(((uint)h) << 16);
}

// ---------- edge weight MLP; ONE packed uint64 atomic: high24=count, low40=deg*2^20
__global__ void k_edge(const int* __restrict__ eid, const int* __restrict__ epos,
                       const float* __restrict__ id_emb, const float* __restrict__ pos_emb,
                       const float* __restrict__ w1, const float* __restrict__ b1,
                       const float* __restrict__ w2, const float* __restrict__ b2,
                       const int* __restrict__ ei, float* __restrict__ ew,
                       unsigned long long* __restrict__ cnt64, int E) {
    __shared__ float sW1[100];
    __shared__ float sB1[10];
    __shared__ float sW2[10];
    __shared__ float sB2;
    int t = threadIdx.x;
    if (t < 100) sW1[t] = w1[t];
    if (t < 10) { sB1[t] = b1[t]; sW2[t] = w2[t]; }
    if (t == 0) sB2 = b2[0];
    __syncthreads();
    int e = blockIdx.x * blockDim.x + t;
    if (e >= E) return;
    int id = eid[e];
    int p  = epos[e];
    const float4* ide = (const float4*)(id_emb + (size_t)id * 8);
    float4 fa = ide[0], fb = ide[1];
    float f[10];
    f[0] = fa.x; f[1] = fa.y; f[2] = fa.z; f[3] = fa.w;
    f[4] = fb.x; f[5] = fb.y; f[6] = fb.z; f[7] = fb.w;
    f[8] = pos_emb[p * 2 + 0];
    f[9] = pos_emb[p * 2 + 1];
    float acc = sB2;
#pragma unroll
    for (int j = 0; j < 10; j++) {
        float h = sB1[j];
#pragma unroll
        for (int i = 0; i < 10; i++) h += f[i] * sW1[i * 10 + j];
        h = fmaxf(h, 0.f);
        acc += h * sW2[j];
    }
    float w = 1.f / (1.f + expf(-acc));
    ew[e] = w;
    int dst = ei[E + e];
    unsigned long long pack = (1ull << 40) + (unsigned long long)(w * 1048576.0f + 0.5f);
    atomicAdd(&cnt64[dst], pack);
}

// ---------- scan phase a (+dinv from cnt64 + nf4 pack + gsum zero + wprep blocks 0..63)
__global__ void k_scan_a(const unsigned long long* __restrict__ cnt64,
                         int* __restrict__ row_ptr, int* __restrict__ bsums,
                         float* __restrict__ deg, const float* __restrict__ nf,
                         float4* __restrict__ nf4, float* __restrict__ gsum,
                         const float* __restrict__ w2, const float* __restrict__ aw1,
                         ushort* __restrict__ w2h, ushort* __restrict__ w2l,
                         ushort* __restrict__ a1h, ushort* __restrict__ a1l, int N) {
    __shared__ int s[256];
    int b = blockIdx.x, t = threadIdx.x;
    int i = b * 256 + t;
    if (b == 0) gsum[t] = 0.f;
    if (b < 64) {  // wprep: Frag[c][t][L][j] = W[32c+(L>>4)*8+j][16t+(L&15)]
        int gid = b * 256 + t;
        int mat = gid >> 13;
        int rem = gid & 8191;
        int c = rem >> 10;
        int tt = (rem >> 6) & 15;
        int L = rem & 63;
        int k0 = 32 * c + (L >> 4) * 8;
        int n  = 16 * tt + (L & 15);
        const float* W = mat ? aw1 : w2;
        ushort* H  = mat ? a1h : w2h;
        ushort* Lo = mat ? a1l : w2l;
        short8 hv, lv;
#pragma unroll
        for (int j = 0; j < 8; j++) {
            float x = W[(size_t)(k0 + j) * HID + n];
            ushort h = bf16_rne(x);
            hv[j] = (short)h;
            lv[j] = (short)bf16_rne(x - bf16_to_f(h));
        }
        size_t off = (size_t)rem * 8;
        *(short8*)(H + off) = hv;
        *(short8*)(Lo + off) = lv;
    }
    int v = 0;
    if (i < N) {
        unsigned long long cv = cnt64[i];
        v = (int)(cv >> 40);
        float degf = (float)(cv & 0xFFFFFFFFFFull) * (1.0f / 1048576.0f);
        deg[i] = 1.f / sqrtf(degf + 1.f);
        nf4[i] = make_float4(nf[i * 3 + 0], nf[i * 3 + 1], nf[i * 3 + 2], 0.f);
    }
    s[t] = v;
    __syncthreads();
    for (int off = 1; off < 256; off <<= 1) {
        int u = (t >= off) ? s[t - off] : 0;
        __syncthreads();
        s[t] += u;
        __syncthreads();
    }
    int incl = s[t];
    if (i < N) row_ptr[i] = incl - v;
    if (t == 255) bsums[b] = incl;
}

// ---------- scan phase c: per-block offset from bsums prefix; copy to cursor
__global__ void k_scan_c(int* __restrict__ row_ptr, int* __restrict__ cursor,
                         const int* __restrict__ bsums, int N, int NB) {
    __shared__ int s[256];
    int b = blockIdx.x, t = threadIdx.x;
    int v = (t < NB) ? bsums[t] : 0;
    s[t] = (t < b) ? v : 0;
    __syncthreads();
    for (int off = 128; off > 0; off >>= 1) {
        if (t < off) s[t] += s[t + off];
        __syncthreads();
    }
    int boff = s[0];
    int i = b * 256 + t;
    if (i < N) {
        int rp = row_ptr[i] + boff;
        row_ptr[i] = rp;
        cursor[i] = rp;
    }
    if (b == NB - 1) {
        __syncthreads();
        s[t] = (t < NB) ? bsums[t] : 0;
        __syncthreads();
        for (int off = 128; off > 0; off >>= 1) {
            if (t < off) s[t] += s[t + off];
            __syncthreads();
        }
        if (t == 0) row_ptr[N] = s[0];
    }
}

// ---------- fill CSR, 2 edges/thread (two coalesced halves, independent atomic chains)
__global__ void k_fill(const int* __restrict__ ei, const float* __restrict__ ew,
                       const float* __restrict__ dinv, int* __restrict__ cursor,
                       int2* __restrict__ csr, int E, int Eh) {
    int g = blockIdx.x * blockDim.x + threadIdx.x;
    if (g < Eh) {
        int src = ei[g];
        int dst = ei[E + g];
        float norm = dinv[src] * ew[g] * dinv[dst];
        int slot = atomicAdd(&cursor[dst], 1);
        csr[slot] = make_int2(src, __float_as_int(norm));
    }
    int e2 = g + Eh;
    if (e2 < E) {
        int src = ei[e2];
        int dst = ei[E + e2];
        float norm = dinv[src] * ew[e2] * dinv[dst];
        int slot = atomicAdd(&cursor[dst], 1);
        csr[slot] = make_int2(src, __float_as_int(norm));
    }
}

// ---------- layer-1 aggregation, 8-wide batched loads
__global__ void k_agg3(const int* __restrict__ row_ptr, const int2* __restrict__ csr,
                       const float4* __restrict__ nf4, const float* __restrict__ dinv,
                       float4* __restrict__ T3, int N) {
    int n = blockIdx.x * blockDim.x + threadIdx.x;
    if (n >= N) return;
    int s = row_ptr[n];
    int e = row_ptr[n + 1];
    float ax = 0.f, ay = 0.f, az = 0.f;
    int i = s;
    for (; i + 8 <= e; i += 8) {
        int2 c[8];
        float4 t[8];
#pragma unroll
        for (int j = 0; j < 8; j++) c[j] = csr[i + j];
#pragma unroll
        for (int j = 0; j < 8; j++) t[j] = nf4[c[j].x];
#pragma unroll
        for (int j = 0; j < 8; j++) {
            float w = __int_as_float(c[j].y);
            ax = fmaf(w, t[j].x, ax);
            ay = fmaf(w, t[j].y, ay);
            az = fmaf(w, t[j].z, az);
        }
    }
    for (; i < e; i++) {
        int2 sn = csr[i];
        float w = __int_as_float(sn.y);
        float4 v = nf4[sn.x];
        ax = fmaf(w, v.x, ax);
        ay = fmaf(w, v.y, ay);
        az = fmaf(w, v.z, az);
    }
    float d = dinv[n];
    float dd = d * d;
    float4 v = nf4[n];
    ax = fmaf(dd, v.x, ax);
    ay = fmaf(dd, v.y, ay);
    az = fmaf(dd, v.z, az);
    T3[n] = make_float4(ax, ay, az, 0.f);
}

// ---------- per-edge x1-recompute + accumulate helper
__device__ __forceinline__ void gf_edge(float4 t, float wgt,
                                        const float4& w0, const float4& w1,
                                        const float4& w2, const float4& bv, float4& acc) {
    float xx = fmaxf(fmaf(t.x, w0.x, fmaf(t.y, w1.x, fmaf(t.z, w2.x, bv.x))), 0.f);
    float xy = fmaxf(fmaf(t.x, w0.y, fmaf(t.y, w1.y, fmaf(t.z, w2.y, bv.y))), 0.f);
    float xz = fmaxf(fmaf(t.x, w0.z, fmaf(t.y, w1.z, fmaf(t.z, w2.z, bv.z))), 0.f);
    float xw = fmaxf(fmaf(t.x, w0.w, fmaf(t.y, w1.w, fmaf(t.z, w2.w, bv.w))), 0.f);
    acc.x = fmaf(wgt, xx, acc.x);
    acc.y = fmaf(wgt, xy, acc.y);
    acc.z = fmaf(wgt, xz, acc.z);
    acc.w = fmaf(wgt, xw, acc.w);
}

// ---------- fused layer-2 aggregation, 8-wide batched loads; writes A as bf16 hi/lo
__global__ void k_gatherfused(const int* __restrict__ row_ptr, const int2* __restrict__ csr,
                              const float4* __restrict__ T3, const float* __restrict__ dinv,
                              const float* __restrict__ cw, const float* __restrict__ cb,
                              ushort* __restrict__ Ah, ushort* __restrict__ Al, int N) {
    int lane = threadIdx.x & 63;
    int wv = threadIdx.x >> 6;
    int n = blockIdx.x * 4 + wv;
    if (n >= N) return;
    const float4 w0 = *(const float4*)(cw + 4 * lane);
    const float4 w1 = *(const float4*)(cw + HID + 4 * lane);
    const float4 w2 = *(const float4*)(cw + 2 * HID + 4 * lane);
    const float4 bv = *(const float4*)(cb + 4 * lane);
    int s = row_ptr[n];
    int e = row_ptr[n + 1];
    float4 acc = make_float4(0.f, 0.f, 0.f, 0.f);
    int i = s;
    for (; i + 8 <= e; i += 8) {
        int2 c[8];
        float4 t[8];
#pragma unroll
        for (int j = 0; j < 8; j++) c[j] = csr[i + j];
#pragma unroll
        for (int j = 0; j < 8; j++) t[j] = T3[c[j].x];
#pragma unroll
        for (int j = 0; j < 8; j++)
            gf_edge(t[j], __int_as_float(c[j].y), w0, w1, w2, bv, acc);
    }
    for (; i < e; i++) {
        int2 sn = csr[i];
        gf_edge(T3[sn.x], __int_as_float(sn.y), w0, w1, w2, bv, acc);
    }
    float d = dinv[n];
    gf_edge(T3[n], d * d, w0, w1, w2, bv, acc);
    ushort4 hv, lv;
    ushort h;
    h = bf16_rne(acc.x); hv.x = h; lv.x = bf16_rne(acc.x - bf16_to_f(h));
    h = bf16_rne(acc.y); hv.y = h; lv.y = bf16_rne(acc.y - bf16_to_f(h));
    h = bf16_rne(acc.z); hv.z = h; lv.z = bf16_rne(acc.z - bf16_to_f(h));
    h = bf16_rne(acc.w); hv.w = h; lv.w = bf16_rne(acc.w - bf16_to_f(h));
    size_t base = (size_t)n * HID + lane * 4;
    *(ushort4*)(Ah + base) = hv;
    *(ushort4*)(Al + base) = lv;
}

// ================= MFMA double GEMM, 64-row tile, 4 nt x 4 mt per wave,
// explicit double-buffered fragment prefetch (R18-proven config)
#define ASTRIDE 264

__global__ __launch_bounds__(256, 2) void k_gemm_mfma(
        const ushort* __restrict__ Ah, const ushort* __restrict__ Al,
        const float* __restrict__ b2,
        const ushort* __restrict__ w2h, const ushort* __restrict__ w2l,
        const ushort* __restrict__ a1h, const ushort* __restrict__ a1l,
        float* __restrict__ P, float* __restrict__ gsum, int N) {
    __shared__ ushort Hs[64 * ASTRIDE];
    __shared__ ushort Ls[64 * ASTRIDE];
    int tid = threadIdx.x;
    int n0 = blockIdx.x * 64;
    int w = tid >> 6;
    int L = tid & 63;
    int quad = L >> 4, ln = L & 15;

    int arow[4];
#pragma unroll
    for (int mt = 0; mt < 4; mt++) {
        int r = n0 + mt * 16 + ln;
        arow[mt] = (r < N) ? r : (N - 1);
    }

    floatx4 acc[4][4];
#pragma unroll
    for (int i = 0; i < 4; i++)
#pragma unroll
        for (int j = 0; j < 4; j++) acc[i][j] = 0.f;
    {
        short8 pah[2][4], pal[2][4], pbh[2][4], pbl[2][4];
#pragma unroll
        for (int mt = 0; mt < 4; mt++) {
            size_t ab = (size_t)arow[mt] * HID + quad * 8;
            pah[0][mt] = *(const short8*)(Ah + ab);
            pal[0][mt] = *(const short8*)(Al + ab);
        }
#pragma unroll
        for (int nt = 0; nt < 4; nt++) {
            size_t off = ((size_t)(4 * w + nt) * 64 + L) * 8;
            pbh[0][nt] = *(const short8*)(w2h + off);
            pbl[0][nt] = *(const short8*)(w2l + off);
        }
#pragma unroll
        for (int c = 0; c < 8; c++) {
            int cur = c & 1, nxt = cur ^ 1;
            if (c < 7) {
#pragma unroll
                for (int mt = 0; mt < 4; mt++) {
                    size_t ab = (size_t)arow[mt] * HID + 32 * (c + 1) + quad * 8;
                    pah[nxt][mt] = *(const short8*)(Ah + ab);
                    pal[nxt][mt] = *(const short8*)(Al + ab);
                }
#pragma unroll
                for (int nt = 0; nt < 4; nt++) {
                    size_t off = ((size_t)((c + 1) * 16 + 4 * w + nt) * 64 + L) * 8;
                    pbh[nxt][nt] = *(const short8*)(w2h + off);
                    pbl[nxt][nt] = *(const short8*)(w2l + off);
                }
            }
#pragma unroll
            for (int nt = 0; nt < 4; nt++) {
#pragma unroll
                for (int mt = 0; mt < 4; mt++) {
                    acc[nt][mt] = __builtin_amdgcn_mfma_f32_16x16x32_bf16(pah[cur][mt], pbh[cur][nt], acc[nt][mt], 0, 0, 0);
                    acc[nt][mt] = __builtin_amdgcn_mfma_f32_16x16x32_bf16(pah[cur][mt], pbl[cur][nt], acc[nt][mt], 0, 0, 0);
                    acc[nt][mt] = __builtin_amdgcn_mfma_f32_16x16x32_bf16(pal[cur][mt], pbh[cur][nt], acc[nt][mt], 0, 0, 0);
                }
            }
        }
    }

#pragma unroll
    for (int nt = 0; nt < 4; nt++) {
        int col = (4 * w + nt) * 16 + ln;
        float bb = b2[col];
        float s = 0.f;
#pragma unroll
        for (int mt = 0; mt < 4; mt++) {
#pragma unroll
            for (int r = 0; r < 4; r++) {
                int row = n0 + mt * 16 + quad * 4 + r;
                float v = fmaxf(acc[nt][mt][r] + bb, 0.f);
                acc[nt][mt][r] = v;
                if (row < N) s += v;
            }
        }
        s += __shfl_down(s, 32, 64);
        s += __shfl_down(s, 16, 64);
        if (L < 16) atomicAdd(&gsum[col], s);
    }

#pragma unroll
    for (int nt = 0; nt < 4; nt++) {
        int col = (4 * w + nt) * 16 + ln;
#pragma unroll
        for (int mt = 0; mt < 4; mt++) {
#pragma unroll
            for (int r = 0; r < 4; r++) {
                int row = mt * 16 + quad * 4 + r;
                float v = acc[nt][mt][r];
                ushort h = bf16_rne(v);
                Hs[row * ASTRIDE + col] = h;
                Ls[row * ASTRIDE + col] = bf16_rne(v - bf16_to_f(h));
            }
        }
    }
    __syncthreads();

    floatx4 acc2[4][4];
#pragma unroll
    for (int i = 0; i < 4; i++)
#pragma unroll
        for (int j = 0; j < 4; j++) acc2[i][j] = 0.f;
    {
        short8 pbh[2][4], pbl[2][4];
#pragma unroll
        for (int nt = 0; nt < 4; nt++) {
            size_t off = ((size_t)(4 * w + nt) * 64 + L) * 8;
            pbh[0][nt] = *(const short8*)(a1h + off);
            pbl[0][nt] = *(const short8*)(a1l + off);
        }
#pragma unroll
        for (int c = 0; c < 8; c++) {
            int cur = c & 1, nxt = cur ^ 1;
            if (c < 7) {
#pragma unroll
                for (int nt = 0; nt < 4; nt++) {
                    size_t off = ((size_t)((c + 1) * 16 + 4 * w + nt) * 64 + L) * 8;
                    pbh[nxt][nt] = *(const short8*)(a1h + off);
                    pbl[nxt][nt] = *(const short8*)(a1l + off);
                }
            }
            short8 ahf[4], alf[4];
#pragma unroll
            for (int mt = 0; mt < 4; mt++) {
                int base = (mt * 16 + ln) * ASTRIDE + 32 * c + quad * 8;
                ahf[mt] = *(const short8*)&Hs[base];
                alf[mt] = *(const short8*)&Ls[base];
            }
#pragma unroll
            for (int nt = 0; nt < 4; nt++) {
#pragma unroll
                for (int mt = 0; mt < 4; mt++) {
                    acc2[nt][mt] = __builtin_amdgcn_mfma_f32_16x16x32_bf16(ahf[mt], pbh[cur][nt], acc2[nt][mt], 0, 0, 0);
                    acc2[nt][mt] = __builtin_amdgcn_mfma_f32_16x16x32_bf16(ahf[mt], pbl[cur][nt], acc2[nt][mt], 0, 0, 0);
                    acc2[nt][mt] = __builtin_amdgcn_mfma_f32_16x16x32_bf16(alf[mt], pbh[cur][nt], acc2[nt][mt], 0, 0, 0);
                }
            }
        }
    }

#pragma unroll
    for (int nt = 0; nt < 4; nt++) {
        int col = (4 * w + nt) * 16 + ln;
#pragma unroll
        for (int mt = 0; mt < 4; mt++) {
#pragma unroll
            for (int r = 0; r < 4; r++) {
                int row = n0 + mt * 16 + quad * 4 + r;
                if (row < N) P[(size_t)row * HID + col] = acc2[nt][mt][r];
            }
        }
    }
}

// ---------- heads A (12 blocks): b<8 -> c1 slice; b>=8 -> gbias slice
__global__ void k_headsA(const float* __restrict__ gsum,
                         const float* __restrict__ cw1, const float* __restrict__ cb1,
                         float* __restrict__ c1g,
                         const float* __restrict__ aw1, const float* __restrict__ ab1,
                         float* __restrict__ gbias,
                         const float* __restrict__ cb3, float* __restrict__ sv_out,
                         float invN) {
    __shared__ float part[4][64];
    int b = blockIdx.x, t = threadIdx.x;
    int c = t & 63;
    int kr = t >> 6;
    if (b == 0 && t == 0) sv_out[0] = cb3[0];
    if (b < 8) {
        int col = b * 64 + c;
        float s = 0.f;
        for (int k = kr * 128; k < kr * 128 + 128; k++)
            s += gsum[k & (HID - 1)] * invN * cw1[(size_t)k * 512 + col];
        part[kr][c] = s;
        __syncthreads();
        if (kr == 0) {
            float v = cb1[col] + part[0][c] + part[1][c] + part[2][c] + part[3][c];
            c1g[col] = fmaxf(v, 0.f);
        }
    } else {
        int col = (b - 8) * 64 + c;
        float s = 0.f;
        for (int k = kr * 64; k < kr * 64 + 64; k++)
            s += gsum[k] * invN * aw1[(size_t)(HID + k) * HID + col];
        part[kr][c] = s;
        __syncthreads();
        if (kr == 0)
            gbias[col] = ab1[col] + part[0][c] + part[1][c] + part[2][c] + part[3][c];
    }
}

// ---------- merged heads B + logits: blocks 0..3 -> critic c2 slice; blocks 4.. -> logits
__global__ void k_headsBL(const float* __restrict__ c1g,
                          const float* __restrict__ cw2, const float* __restrict__ cb2,
                          const float* __restrict__ cw3, float* __restrict__ sv_out,
                          const float* __restrict__ P, const float* __restrict__ gbias,
                          const float* __restrict__ aw2, const float* __restrict__ ab2,
                          float* __restrict__ out, int N) {
    int b = blockIdx.x, t = threadIdx.x;
    if (b < 4) {
        __shared__ float part[4][64];
        int c = t & 63;
        int kr = t >> 6;
        int col = b * 64 + c;
        float s = 0.f;
        for (int k = kr * 128; k < kr * 128 + 128; k++)
            s += c1g[k] * cw2[(size_t)k * HID + col];
        part[kr][c] = s;
        __syncthreads();
        if (kr == 0) {
            float v = fmaxf(cb2[col] + part[0][c] + part[1][c] + part[2][c] + part[3][c], 0.f)
                    * cw3[col];
#pragma unroll
            for (int off = 32; off > 0; off >>= 1) v += __shfl_down(v, off, 64);
            if (c == 0) atomicAdd(sv_out, v);
        }
        return;
    }
    int lane = t & 63;
    int wv = t >> 6;
    int n = (b - 4) * 4 + wv;
    if (n >= N) return;
    float4 p = *(const float4*)(P + (size_t)n * HID + 4 * lane);
    float4 gb = *(const float4*)(gbias + 4 * lane);
    float4 w2 = *(const float4*)(aw2 + 4 * lane);
    float v = fmaxf(p.x + gb.x, 0.f) * w2.x
            + fmaxf(p.y + gb.y, 0.f) * w2.y
            + fmaxf(p.z + gb.z, 0.f) * w2.z
            + fmaxf(p.w + gb.w, 0.f) * w2.w;
#pragma unroll
    for (int off = 32; off > 0; off >>= 1) v += __shfl_down(v, off, 64);
    if (lane == 0) out[n] = v + ab2[0];
}

extern "C" void kernel_launch(void* const* d_in, const int* in_sizes, int n_in,
                              void* d_out, int out_size, void* d_ws, size_t ws_size,
                              hipStream_t stream) {
    const float* nf      = (const float*)d_in[0];
    const int*   ei      = (const int*)d_in[1];
    const int*   eid     = (const int*)d_in[2];
    const int*   epos    = (const int*)d_in[3];
    const float* id_emb  = (const float*)d_in[4];
    const float* pos_emb = (const float*)d_in[5];
    const float* ew_w1   = (const float*)d_in[6];
    const float* ew_b1   = (const float*)d_in[7];
    const float* ew_w2   = (const float*)d_in[8];
    const float* ew_b2   = (const float*)d_in[9];
    const float* c1w     = (const float*)d_in[10];
    const float* c1b     = (const float*)d_in[11];
    const float* c2w     = (const float*)d_in[12];
    const float* c2b     = (const float*)d_in[13];
    const float* aw1     = (const float*)d_in[14];
    const float* ab1     = (const float*)d_in[15];
    const float* aw2     = (const float*)d_in[16];
    const float* ab2     = (const float*)d_in[17];
    const float* cw1     = (const float*)d_in[18];
    const float* cb1     = (const float*)d_in[19];
    const float* cw2     = (const float*)d_in[20];
    const float* cb2     = (const float*)d_in[21];
    const float* cw3     = (const float*)d_in[22];
    const float* cb3     = (const float*)d_in[23];

    int N = in_sizes[0] / 3;
    int E = in_sizes[2];
    int NB = (N + 255) / 256;
    int Eh = (E + 1) / 2;
    float invN = 1.f / (float)N;

    char* ws = (char*)d_ws;
    unsigned long long* cnt64 = (unsigned long long*)ws;  ws += (size_t)N * 8;
    float* gsum     = (float*)ws;                         ws += HID * 4;
    float* deg      = (float*)ws;                         ws += (size_t)N * 4;
    ushort* Ah      = (ushort*)ws;                        ws += (size_t)N * HID * 2;
    ushort* Al      = (ushort*)ws;                        ws += (size_t)N * HID * 2;
    float* P        = (float*)ws;                         ws += (size_t)N * HID * 4;
    float* ew       = (float*)ws;                         ws += (size_t)E * 4;
    int2*  csr      = (int2*)ws;                          ws += (size_t)E * 8;
    int*   row_ptr  = (int*)ws;                           ws += (size_t)(N + 1) * 4;
    int*   cursor   = (int*)ws;                           ws += (size_t)N * 4;
    int*   bsums    = (int*)ws;                           ws += 256 * 4;
    float4* T3      = (float4*)ws;                        ws += (size_t)N * 16;
    float4* nf4     = (float4*)ws;                        ws += (size_t)N * 16;
    float* gbias    = (float*)ws;                         ws += HID * 4;
    float* c1g      = (float*)ws;                         ws += 512 * 4;
    ushort* w2h     = (ushort*)ws;                        ws += 65536 * 2;
    ushort* w2l     = (ushort*)ws;                        ws += 65536 * 2;
    ushort* a1h     = (ushort*)ws;                        ws += 65536 * 2;
    ushort* a1l     = (ushort*)ws;                        ws += 65536 * 2;

    float* out = (float*)d_out;  // [N] logits + [1] state value

    // --- zero cnt64 (gsum zeroed in k_scan_a)
    hipMemsetAsync(cnt64, 0, (size_t)N * 8, stream);

    // --- edge MLP + packed degree/count atomic
    k_edge<<<(E + 255) / 256, 256, 0, stream>>>(eid, epos, id_emb, pos_emb,
                                                ew_w1, ew_b1, ew_w2, ew_b2, ei, ew, cnt64, E);

    // --- scan a (+ dinv + nf4 pack + gsum zero + wprep), then c
    k_scan_a<<<NB, 256, 0, stream>>>(cnt64, row_ptr, bsums, deg, nf, nf4, gsum,
                                     c2w, aw1, w2h, w2l, a1h, a1l, N);
    k_scan_c<<<NB, 256, 0, stream>>>(row_ptr, cursor, bsums, N, NB);

    // --- fill CSR (2 edges/thread)
    k_fill<<<(Eh + 255) / 256, 256, 0, stream>>>(ei, ew, deg, cursor, csr, E, Eh);

    // --- layer 1 aggregate on raw features (8-wide batched)
    k_agg3<<<(N + 255) / 256, 256, 0, stream>>>(row_ptr, csr, nf4, deg, T3, N);

    // --- layer 2 aggregate (8-wide batched); writes A as bf16 hi/lo
    k_gatherfused<<<(N + 3) / 4, 256, 0, stream>>>(row_ptr, csr, T3, deg, c1w, c1b, Ah, Al, N);

    // --- MFMA fused conv2-GEMM + actor-GEMM (+ colsum); 64-row tiles, prefetched
    k_gemm_mfma<<<(N + 63) / 64, 256, 0, stream>>>(Ah, Al, c2b, w2h, w2l, a1h, a1l, P, gsum, N);

    // --- heads A (c1 + gbias), then merged heads B + logits
    k_headsA<<<12, 256, 0, stream>>>(gsum, cw1, cb1, c1g, aw1, ab1, gbias,
                                     cb3, out + N, invN);
    k_headsBL<<<4 + (N + 3) / 4, 256, 0, stream>>>(c1g, cw2, cb2, cw3, out + N,
                                                   P, gbias, aw2, ab2, out, N);
}

// Round 21
// 370.891 us; speedup vs baseline: 1.0531x; 1.0130x over previous
//
#include <hip/hip_runtime.h>
#include <math.h>

#define HID 256

typedef __attribute__((ext_vector_type(8))) short short8;
typedef __attribute__((ext_vector_type(4))) float floatx4;

__device__ __forceinline__ ushort bf16_rne(float x) {
    uint u = __float_as_uint(x);
    uint r = (u + 0x7FFFu + ((u >> 16) & 1u)) >> 16;
    return (ushort)r;
}
__device__ __forceinline__ float bf16_to_f(ushort h) {
    return __uint_as_float(((uint)h) << 16);
}

// ---------- edge weight MLP; ONE packed uint64 atomic: high24=count, low40=deg*2^20
__global__ void k_edge(const int* __restrict__ eid, const int* __restrict__ epos,
                       const float* __restrict__ id_emb, const float* __restrict__ pos_emb,
                       const float* __restrict__ w1, const float* __restrict__ b1,
                       const float* __restrict__ w2, const float* __restrict__ b2,
                       const int* __restrict__ ei, float* __restrict__ ew,
                       unsigned long long* __restrict__ cnt64, int E) {
    __shared__ float sW1[100];
    __shared__ float sB1[10];
    __shared__ float sW2[10];
    __shared__ float sB2;
    int t = threadIdx.x;
    if (t < 100) sW1[t] = w1[t];
    if (t < 10) { sB1[t] = b1[t]; sW2[t] = w2[t]; }
    if (t == 0) sB2 = b2[0];
    __syncthreads();
    int e = blockIdx.x * blockDim.x + t;
    if (e >= E) return;
    int id = eid[e];
    int p  = epos[e];
    const float4* ide = (const float4*)(id_emb + (size_t)id * 8);
    float4 fa = ide[0], fb = ide[1];
    float f[10];
    f[0] = fa.x; f[1] = fa.y; f[2] = fa.z; f[3] = fa.w;
    f[4] = fb.x; f[5] = fb.y; f[6] = fb.z; f[7] = fb.w;
    f[8] = pos_emb[p * 2 + 0];
    f[9] = pos_emb[p * 2 + 1];
    float acc = sB2;
#pragma unroll
    for (int j = 0; j < 10; j++) {
        float h = sB1[j];
#pragma unroll
        for (int i = 0; i < 10; i++) h += f[i] * sW1[i * 10 + j];
        h = fmaxf(h, 0.f);
        acc += h * sW2[j];
    }
    float w = 1.f / (1.f + expf(-acc));
    ew[e] = w;
    int dst = ei[E + e];
    unsigned long long pack = (1ull << 40) + (unsigned long long)(w * 1048576.0f + 0.5f);
    atomicAdd(&cnt64[dst], pack);
}

// ---------- scan phase a (+dinv from cnt64 + nf4 pack + gsum zero + wprep blocks 0..63)
__global__ void k_scan_a(const unsigned long long* __restrict__ cnt64,
                         int* __restrict__ row_ptr, int* __restrict__ bsums,
                         float* __restrict__ deg, const float* __restrict__ nf,
                         float4* __restrict__ nf4, float* __restrict__ gsum,
                         const float* __restrict__ w2, const float* __restrict__ aw1,
                         ushort* __restrict__ w2h, ushort* __restrict__ w2l,
                         ushort* __restrict__ a1h, ushort* __restrict__ a1l, int N) {
    __shared__ int s[256];
    int b = blockIdx.x, t = threadIdx.x;
    int i = b * 256 + t;
    if (b == 0) gsum[t] = 0.f;
    if (b < 64) {  // wprep: Frag[c][t][L][j] = W[32c+(L>>4)*8+j][16t+(L&15)]
        int gid = b * 256 + t;
        int mat = gid >> 13;
        int rem = gid & 8191;
        int c = rem >> 10;
        int tt = (rem >> 6) & 15;
        int L = rem & 63;
        int k0 = 32 * c + (L >> 4) * 8;
        int n  = 16 * tt + (L & 15);
        const float* W = mat ? aw1 : w2;
        ushort* H  = mat ? a1h : w2h;
        ushort* Lo = mat ? a1l : w2l;
        short8 hv, lv;
#pragma unroll
        for (int j = 0; j < 8; j++) {
            float x = W[(size_t)(k0 + j) * HID + n];
            ushort h = bf16_rne(x);
            hv[j] = (short)h;
            lv[j] = (short)bf16_rne(x - bf16_to_f(h));
        }
        size_t off = (size_t)rem * 8;
        *(short8*)(H + off) = hv;
        *(short8*)(Lo + off) = lv;
    }
    int v = 0;
    if (i < N) {
        unsigned long long cv = cnt64[i];
        v = (int)(cv >> 40);
        float degf = (float)(cv & 0xFFFFFFFFFFull) * (1.0f / 1048576.0f);
        deg[i] = 1.f / sqrtf(degf + 1.f);
        nf4[i] = make_float4(nf[i * 3 + 0], nf[i * 3 + 1], nf[i * 3 + 2], 0.f);
    }
    s[t] = v;
    __syncthreads();
    for (int off = 1; off < 256; off <<= 1) {
        int u = (t >= off) ? s[t - off] : 0;
        __syncthreads();
        s[t] += u;
        __syncthreads();
    }
    int incl = s[t];
    if (i < N) row_ptr[i] = incl - v;
    if (t == 255) bsums[b] = incl;
}

// ---------- scan phase c: per-block offset from bsums prefix; copy to cursor
__global__ void k_scan_c(int* __restrict__ row_ptr, int* __restrict__ cursor,
                         const int* __restrict__ bsums, int N, int NB) {
    __shared__ int s[256];
    int b = blockIdx.x, t = threadIdx.x;
    int v = (t < NB) ? bsums[t] : 0;
    s[t] = (t < b) ? v : 0;
    __syncthreads();
    for (int off = 128; off > 0; off >>= 1) {
        if (t < off) s[t] += s[t + off];
        __syncthreads();
    }
    int boff = s[0];
    int i = b * 256 + t;
    if (i < N) {
        int rp = row_ptr[i] + boff;
        row_ptr[i] = rp;
        cursor[i] = rp;
    }
    if (b == NB - 1) {
        __syncthreads();
        s[t] = (t < NB) ? bsums[t] : 0;
        __syncthreads();
        for (int off = 128; off > 0; off >>= 1) {
            if (t < off) s[t] += s[t + off];
            __syncthreads();
        }
        if (t == 0) row_ptr[N] = s[0];
    }
}

// ---------- fill CSR, 2 edges/thread (two coalesced halves, independent atomic chains)
__global__ void k_fill(const int* __restrict__ ei, const float* __restrict__ ew,
                       const float* __restrict__ dinv, int* __restrict__ cursor,
                       int2* __restrict__ csr, int E, int Eh) {
    int g = blockIdx.x * blockDim.x + threadIdx.x;
    if (g < Eh) {
        int src = ei[g];
        int dst = ei[E + g];
        float norm = dinv[src] * ew[g] * dinv[dst];
        int slot = atomicAdd(&cursor[dst], 1);
        csr[slot] = make_int2(src, __float_as_int(norm));
    }
    int e2 = g + Eh;
    if (e2 < E) {
        int src = ei[e2];
        int dst = ei[E + e2];
        float norm = dinv[src] * ew[e2] * dinv[dst];
        int slot = atomicAdd(&cursor[dst], 1);
        csr[slot] = make_int2(src, __float_as_int(norm));
    }
}

// ---------- layer-1 aggregation, 8-wide batched loads
__global__ void k_agg3(const int* __restrict__ row_ptr, const int2* __restrict__ csr,
                       const float4* __restrict__ nf4, const float* __restrict__ dinv,
                       float4* __restrict__ T3, int N) {
    int n = blockIdx.x * blockDim.x + threadIdx.x;
    if (n >= N) return;
    int s = row_ptr[n];
    int e = row_ptr[n + 1];
    float ax = 0.f, ay = 0.f, az = 0.f;
    int i = s;
    for (; i + 8 <= e; i += 8) {
        int2 c[8];
        float4 t[8];
#pragma unroll
        for (int j = 0; j < 8; j++) c[j] = csr[i + j];
#pragma unroll
        for (int j = 0; j < 8; j++) t[j] = nf4[c[j].x];
#pragma unroll
        for (int j = 0; j < 8; j++) {
            float w = __int_as_float(c[j].y);
            ax = fmaf(w, t[j].x, ax);
            ay = fmaf(w, t[j].y, ay);
            az = fmaf(w, t[j].z, az);
        }
    }
    for (; i < e; i++) {
        int2 sn = csr[i];
        float w = __int_as_float(sn.y);
        float4 v = nf4[sn.x];
        ax = fmaf(w, v.x, ax);
        ay = fmaf(w, v.y, ay);
        az = fmaf(w, v.z, az);
    }
    float d = dinv[n];
    float dd = d * d;
    float4 v = nf4[n];
    ax = fmaf(dd, v.x, ax);
    ay = fmaf(dd, v.y, ay);
    az = fmaf(dd, v.z, az);
    T3[n] = make_float4(ax, ay, az, 0.f);
}

// ---------- per-edge x1-recompute + accumulate helper
__device__ __forceinline__ void gf_edge(float4 t, float wgt,
                                        const float4& w0, const float4& w1,
                                        const float4& w2, const float4& bv, float4& acc) {
    float xx = fmaxf(fmaf(t.x, w0.x, fmaf(t.y, w1.x, fmaf(t.z, w2.x, bv.x))), 0.f);
    float xy = fmaxf(fmaf(t.x, w0.y, fmaf(t.y, w1.y, fmaf(t.z, w2.y, bv.y))), 0.f);
    float xz = fmaxf(fmaf(t.x, w0.z, fmaf(t.y, w1.z, fmaf(t.z, w2.z, bv.z))), 0.f);
    float xw = fmaxf(fmaf(t.x, w0.w, fmaf(t.y, w1.w, fmaf(t.z, w2.w, bv.w))), 0.f);
    acc.x = fmaf(wgt, xx, acc.x);
    acc.y = fmaf(wgt, xy, acc.y);
    acc.z = fmaf(wgt, xz, acc.z);
    acc.w = fmaf(wgt, xw, acc.w);
}

// ---------- fused layer-2 aggregation, 8-wide batched loads; writes A as bf16 hi/lo
__global__ void k_gatherfused(const int* __restrict__ row_ptr, const int2* __restrict__ csr,
                              const float4* __restrict__ T3, const float* __restrict__ dinv,
                              const float* __restrict__ cw, const float* __restrict__ cb,
                              ushort* __restrict__ Ah, ushort* __restrict__ Al, int N) {
    int lane = threadIdx.x & 63;
    int wv = threadIdx.x >> 6;
    int n = blockIdx.x * 4 + wv;
    if (n >= N) return;
    const float4 w0 = *(const float4*)(cw + 4 * lane);
    const float4 w1 = *(const float4*)(cw + HID + 4 * lane);
    const float4 w2 = *(const float4*)(cw + 2 * HID + 4 * lane);
    const float4 bv = *(const float4*)(cb + 4 * lane);
    int s = row_ptr[n];
    int e = row_ptr[n + 1];
    float4 acc = make_float4(0.f, 0.f, 0.f, 0.f);
    int i = s;
    for (; i + 8 <= e; i += 8) {
        int2 c[8];
        float4 t[8];
#pragma unroll
        for (int j = 0; j < 8; j++) c[j] = csr[i + j];
#pragma unroll
        for (int j = 0; j < 8; j++) t[j] = T3[c[j].x];
#pragma unroll
        for (int j = 0; j < 8; j++)
            gf_edge(t[j], __int_as_float(c[j].y), w0, w1, w2, bv, acc);
    }
    for (; i < e; i++) {
        int2 sn = csr[i];
        gf_edge(T3[sn.x], __int_as_float(sn.y), w0, w1, w2, bv, acc);
    }
    float d = dinv[n];
    gf_edge(T3[n], d * d, w0, w1, w2, bv, acc);
    ushort4 hv, lv;
    ushort h;
    h = bf16_rne(acc.x); hv.x = h; lv.x = bf16_rne(acc.x - bf16_to_f(h));
    h = bf16_rne(acc.y); hv.y = h; lv.y = bf16_rne(acc.y - bf16_to_f(h));
    h = bf16_rne(acc.z); hv.z = h; lv.z = bf16_rne(acc.z - bf16_to_f(h));
    h = bf16_rne(acc.w); hv.w = h; lv.w = bf16_rne(acc.w - bf16_to_f(h));
    size_t base = (size_t)n * HID + lane * 4;
    *(ushort4*)(Ah + base) = hv;
    *(ushort4*)(Al + base) = lv;
}

// ================= MFMA double GEMM, 64-row tile, 4 nt x 4 mt per wave,
// double-buffered prefetch + PER-BLOCK K-LOOP ROTATION (L2 hot-set decorrelation)
#define ASTRIDE 264

__global__ __launch_bounds__(256, 2) void k_gemm_mfma(
        const ushort* __restrict__ Ah, const ushort* __restrict__ Al,
        const float* __restrict__ b2,
        const ushort* __restrict__ w2h, const ushort* __restrict__ w2l,
        const ushort* __restrict__ a1h, const ushort* __restrict__ a1l,
        float* __restrict__ P, float* __restrict__ gsum, int N) {
    __shared__ ushort Hs[64 * ASTRIDE];
    __shared__ ushort Ls[64 * ASTRIDE];
    int tid = threadIdx.x;
    int n0 = blockIdx.x * 64;
    int boff = blockIdx.x & 7;   // K-phase rotation per block
    int w = tid >> 6;
    int L = tid & 63;
    int quad = L >> 4, ln = L & 15;

    int arow[4];
#pragma unroll
    for (int mt = 0; mt < 4; mt++) {
        int r = n0 + mt * 16 + ln;
        arow[mt] = (r < N) ? r : (N - 1);
    }

    floatx4 acc[4][4];
#pragma unroll
    for (int i = 0; i < 4; i++)
#pragma unroll
        for (int j = 0; j < 4; j++) acc[i][j] = 0.f;
    {
        short8 pah[2][4], pal[2][4], pbh[2][4], pbl[2][4];
#pragma unroll
        for (int mt = 0; mt < 4; mt++) {
            size_t ab = (size_t)arow[mt] * HID + 32 * boff + quad * 8;
            pah[0][mt] = *(const short8*)(Ah + ab);
            pal[0][mt] = *(const short8*)(Al + ab);
        }
#pragma unroll
        for (int nt = 0; nt < 4; nt++) {
            size_t off = ((size_t)(boff * 16 + 4 * w + nt) * 64 + L) * 8;
            pbh[0][nt] = *(const short8*)(w2h + off);
            pbl[0][nt] = *(const short8*)(w2l + off);
        }
#pragma unroll
        for (int cc = 0; cc < 8; cc++) {
            int cur = cc & 1, nxt = cur ^ 1;
            if (cc < 7) {
                int cn = (cc + 1 + boff) & 7;
#pragma unroll
                for (int mt = 0; mt < 4; mt++) {
                    size_t ab = (size_t)arow[mt] * HID + 32 * cn + quad * 8;
                    pah[nxt][mt] = *(const short8*)(Ah + ab);
                    pal[nxt][mt] = *(const short8*)(Al + ab);
                }
#pragma unroll
                for (int nt = 0; nt < 4; nt++) {
                    size_t off = ((size_t)(cn * 16 + 4 * w + nt) * 64 + L) * 8;
                    pbh[nxt][nt] = *(const short8*)(w2h + off);
                    pbl[nxt][nt] = *(const short8*)(w2l + off);
                }
            }
#pragma unroll
            for (int nt = 0; nt < 4; nt++) {
#pragma unroll
                for (int mt = 0; mt < 4; mt++) {
                    acc[nt][mt] = __builtin_amdgcn_mfma_f32_16x16x32_bf16(pah[cur][mt], pbh[cur][nt], acc[nt][mt], 0, 0, 0);
                    acc[nt][mt] = __builtin_amdgcn_mfma_f32_16x16x32_bf16(pah[cur][mt], pbl[cur][nt], acc[nt][mt], 0, 0, 0);
                    acc[nt][mt] = __builtin_amdgcn_mfma_f32_16x16x32_bf16(pal[cur][mt], pbh[cur][nt], acc[nt][mt], 0, 0, 0);
                }
            }
        }
    }

#pragma unroll
    for (int nt = 0; nt < 4; nt++) {
        int col = (4 * w + nt) * 16 + ln;
        float bb = b2[col];
        float s = 0.f;
#pragma unroll
        for (int mt = 0; mt < 4; mt++) {
#pragma unroll
            for (int r = 0; r < 4; r++) {
                int row = n0 + mt * 16 + quad * 4 + r;
                float v = fmaxf(acc[nt][mt][r] + bb, 0.f);
                acc[nt][mt][r] = v;
                if (row < N) s += v;
            }
        }
        s += __shfl_down(s, 32, 64);
        s += __shfl_down(s, 16, 64);
        if (L < 16) atomicAdd(&gsum[col], s);
    }

#pragma unroll
    for (int nt = 0; nt < 4; nt++) {
        int col = (4 * w + nt) * 16 + ln;
#pragma unroll
        for (int mt = 0; mt < 4; mt++) {
#pragma unroll
            for (int r = 0; r < 4; r++) {
                int row = mt * 16 + quad * 4 + r;
                float v = acc[nt][mt][r];
                ushort h = bf16_rne(v);
                Hs[row * ASTRIDE + col] = h;
                Ls[row * ASTRIDE + col] = bf16_rne(v - bf16_to_f(h));
            }
        }
    }
    __syncthreads();

    floatx4 acc2[4][4];
#pragma unroll
    for (int i = 0; i < 4; i++)
#pragma unroll
        for (int j = 0; j < 4; j++) acc2[i][j] = 0.f;
    {
        short8 pbh[2][4], pbl[2][4];
#pragma unroll
        for (int nt = 0; nt < 4; nt++) {
            size_t off = ((size_t)(boff * 16 + 4 * w + nt) * 64 + L) * 8;
            pbh[0][nt] = *(const short8*)(a1h + off);
            pbl[0][nt] = *(const short8*)(a1l + off);
        }
#pragma unroll
        for (int cc = 0; cc < 8; cc++) {
            int cur = cc & 1, nxt = cur ^ 1;
            int c = (cc + boff) & 7;
            if (cc < 7) {
                int cn = (cc + 1 + boff) & 7;
#pragma unroll
                for (int nt = 0; nt < 4; nt++) {
                    size_t off = ((size_t)(cn * 16 + 4 * w + nt) * 64 + L) * 8;
                    pbh[nxt][nt] = *(const short8*)(a1h + off);
                    pbl[nxt][nt] = *(const short8*)(a1l + off);
                }
            }
            short8 ahf[4], alf[4];
#pragma unroll
            for (int mt = 0; mt < 4; mt++) {
                int base = (mt * 16 + ln) * ASTRIDE + 32 * c + quad * 8;
                ahf[mt] = *(const short8*)&Hs[base];
                alf[mt] = *(const short8*)&Ls[base];
            }
#pragma unroll
            for (int nt = 0; nt < 4; nt++) {
#pragma unroll
                for (int mt = 0; mt < 4; mt++) {
                    acc2[nt][mt] = __builtin_amdgcn_mfma_f32_16x16x32_bf16(ahf[mt], pbh[cur][nt], acc2[nt][mt], 0, 0, 0);
                    acc2[nt][mt] = __builtin_amdgcn_mfma_f32_16x16x32_bf16(ahf[mt], pbl[cur][nt], acc2[nt][mt], 0, 0, 0);
                    acc2[nt][mt] = __builtin_amdgcn_mfma_f32_16x16x32_bf16(alf[mt], pbh[cur][nt], acc2[nt][mt], 0, 0, 0);
                }
            }
        }
    }

#pragma unroll
    for (int nt = 0; nt < 4; nt++) {
        int col = (4 * w + nt) * 16 + ln;
#pragma unroll
        for (int mt = 0; mt < 4; mt++) {
#pragma unroll
            for (int r = 0; r < 4; r++) {
                int row = n0 + mt * 16 + quad * 4 + r;
                if (row < N) P[(size_t)row * HID + col] = acc2[nt][mt][r];
            }
        }
    }
}

// ---------- heads A (12 blocks): b<8 -> c1 slice; b>=8 -> gbias slice
__global__ void k_headsA(const float* __restrict__ gsum,
                         const float* __restrict__ cw1, const float* __restrict__ cb1,
                         float* __restrict__ c1g,
                         const float* __restrict__ aw1, const float* __restrict__ ab1,
                         float* __restrict__ gbias,
                         const float* __restrict__ cb3, float* __restrict__ sv_out,
                         float invN) {
    __shared__ float part[4][64];
    int b = blockIdx.x, t = threadIdx.x;
    int c = t & 63;
    int kr = t >> 6;
    if (b == 0 && t == 0) sv_out[0] = cb3[0];
    if (b < 8) {
        int col = b * 64 + c;
        float s = 0.f;
        for (int k = kr * 128; k < kr * 128 + 128; k++)
            s += gsum[k & (HID - 1)] * invN * cw1[(size_t)k * 512 + col];
        part[kr][c] = s;
        __syncthreads();
        if (kr == 0) {
            float v = cb1[col] + part[0][c] + part[1][c] + part[2][c] + part[3][c];
            c1g[col] = fmaxf(v, 0.f);
        }
    } else {
        int col = (b - 8) * 64 + c;
        float s = 0.f;
        for (int k = kr * 64; k < kr * 64 + 64; k++)
            s += gsum[k] * invN * aw1[(size_t)(HID + k) * HID + col];
        part[kr][c] = s;
        __syncthreads();
        if (kr == 0)
            gbias[col] = ab1[col] + part[0][c] + part[1][c] + part[2][c] + part[3][c];
    }
}

// ---------- merged heads B + logits: blocks 0..3 -> critic c2 slice; blocks 4.. -> logits
__global__ void k_headsBL(const float* __restrict__ c1g,
                          const float* __restrict__ cw2, const float* __restrict__ cb2,
                          const float* __restrict__ cw3, float* __restrict__ sv_out,
                          const float* __restrict__ P, const float* __restrict__ gbias,
                          const float* __restrict__ aw2, const float* __restrict__ ab2,
                          float* __restrict__ out, int N) {
    int b = blockIdx.x, t = threadIdx.x;
    if (b < 4) {
        __shared__ float part[4][64];
        int c = t & 63;
        int kr = t >> 6;
        int col = b * 64 + c;
        float s = 0.f;
        for (int k = kr * 128; k < kr * 128 + 128; k++)
            s += c1g[k] * cw2[(size_t)k * HID + col];
        part[kr][c] = s;
        __syncthreads();
        if (kr == 0) {
            float v = fmaxf(cb2[col] + part[0][c] + part[1][c] + part[2][c] + part[3][c], 0.f)
                    * cw3[col];
#pragma unroll
            for (int off = 32; off > 0; off >>= 1) v += __shfl_down(v, off, 64);
            if (c == 0) atomicAdd(sv_out, v);
        }
        return;
    }
    int lane = t & 63;
    int wv = t >> 6;
    int n = (b - 4) * 4 + wv;
    if (n >= N) return;
    float4 p = *(const float4*)(P + (size_t)n * HID + 4 * lane);
    float4 gb = *(const float4*)(gbias + 4 * lane);
    float4 w2 = *(const float4*)(aw2 + 4 * lane);
    float v = fmaxf(p.x + gb.x, 0.f) * w2.x
            + fmaxf(p.y + gb.y, 0.f) * w2.y
            + fmaxf(p.z + gb.z, 0.f) * w2.z
            + fmaxf(p.w + gb.w, 0.f) * w2.w;
#pragma unroll
    for (int off = 32; off > 0; off >>= 1) v += __shfl_down(v, off, 64);
    if (lane == 0) out[n] = v + ab2[0];
}

extern "C" void kernel_launch(void* const* d_in, const int* in_sizes, int n_in,
                              void* d_out, int out_size, void* d_ws, size_t ws_size,
                              hipStream_t stream) {
    const float* nf      = (const float*)d_in[0];
    const int*   ei      = (const int*)d_in[1];
    const int*   eid     = (const int*)d_in[2];
    const int*   epos    = (const int*)d_in[3];
    const float* id_emb  = (const float*)d_in[4];
    const float* pos_emb = (const float*)d_in[5];
    const float* ew_w1   = (const float*)d_in[6];
    const float* ew_b1   = (const float*)d_in[7];
    const float* ew_w2   = (const float*)d_in[8];
    const float* ew_b2   = (const float*)d_in[9];
    const float* c1w     = (const float*)d_in[10];
    const float* c1b     = (const float*)d_in[11];
    const float* c2w     = (const float*)d_in[12];
    const float* c2b     = (const float*)d_in[13];
    const float* aw1     = (const float*)d_in[14];
    const float* ab1     = (const float*)d_in[15];
    const float* aw2     = (const float*)d_in[16];
    const float* ab2     = (const float*)d_in[17];
    const float* cw1     = (const float*)d_in[18];
    const float* cb1     = (const float*)d_in[19];
    const float* cw2     = (const float*)d_in[20];
    const float* cb2     = (const float*)d_in[21];
    const float* cw3     = (const float*)d_in[22];
    const float* cb3     = (const float*)d_in[23];

    int N = in_sizes[0] / 3;
    int E = in_sizes[2];
    int NB = (N + 255) / 256;
    int Eh = (E + 1) / 2;
    float invN = 1.f / (float)N;

    char* ws = (char*)d_ws;
    unsigned long long* cnt64 = (unsigned long long*)ws;  ws += (size_t)N * 8;
    float* gsum     = (float*)ws;                         ws += HID * 4;
    float* deg      = (float*)ws;                         ws += (size_t)N * 4;
    ushort* Ah      = (ushort*)ws;                        ws += (size_t)N * HID * 2;
    ushort* Al      = (ushort*)ws;                        ws += (size_t)N * HID * 2;
    float* P        = (float*)ws;                         ws += (size_t)N * HID * 4;
    float* ew       = (float*)ws;                         ws += (size_t)E * 4;
    int2*  csr      = (int2*)ws;                          ws += (size_t)E * 8;
    int*   row_ptr  = (int*)ws;                           ws += (size_t)(N + 1) * 4;
    int*   cursor   = (int*)ws;                           ws += (size_t)N * 4;
    int*   bsums    = (int*)ws;                           ws += 256 * 4;
    float4* T3      = (float4*)ws;                        ws += (size_t)N * 16;
    float4* nf4     = (float4*)ws;                        ws += (size_t)N * 16;
    float* gbias    = (float*)ws;                         ws += HID * 4;
    float* c1g      = (float*)ws;                         ws += 512 * 4;
    ushort* w2h     = (ushort*)ws;                        ws += 65536 * 2;
    ushort* w2l     = (ushort*)ws;                        ws += 65536 * 2;
    ushort* a1h     = (ushort*)ws;                        ws += 65536 * 2;
    ushort* a1l     = (ushort*)ws;                        ws += 65536 * 2;

    float* out = (float*)d_out;  // [N] logits + [1] state value

    // --- zero cnt64 (gsum zeroed in k_scan_a)
    hipMemsetAsync(cnt64, 0, (size_t)N * 8, stream);

    // --- edge MLP + packed degree/count atomic
    k_edge<<<(E + 255) / 256, 256, 0, stream>>>(eid, epos, id_emb, pos_emb,
                                                ew_w1, ew_b1, ew_w2, ew_b2, ei, ew, cnt64, E);

    // --- scan a (+ dinv + nf4 pack + gsum zero + wprep), then c
    k_scan_a<<<NB, 256, 0, stream>>>(cnt64, row_ptr, bsums, deg, nf, nf4, gsum,
                                     c2w, aw1, w2h, w2l, a1h, a1l, N);
    k_scan_c<<<NB, 256, 0, stream>>>(row_ptr, cursor, bsums, N, NB);

    // --- fill CSR (2 edges/thread)
    k_fill<<<(Eh + 255) / 256, 256, 0, stream>>>(ei, ew, deg, cursor, csr, E, Eh);

    // --- layer 1 aggregate on raw features (8-wide batched)
    k_agg3<<<(N + 255) / 256, 256, 0, stream>>>(row_ptr, csr, nf4, deg, T3, N);

    // --- layer 2 aggregate (8-wide batched); writes A as bf16 hi/lo
    k_gatherfused<<<(N + 3) / 4, 256, 0, stream>>>(row_ptr, csr, T3, deg, c1w, c1b, Ah, Al, N);

    // --- MFMA fused conv2-GEMM + actor-GEMM (+ colsum); 64-row tiles, K-rotated
    k_gemm_mfma<<<(N + 63) / 64, 256, 0, stream>>>(Ah, Al, c2b, w2h, w2l, a1h, a1l, P, gsum, N);

    // --- heads A (c1 + gbias), then merged heads B + logits
    k_headsA<<<12, 256, 0, stream>>>(gsum, cw1, cb1, c1g, aw1, ab1, gbias,
                                     cb3, out + N, invN);
    k_headsBL<<<4 + (N + 3) / 4, 256, 0, stream>>>(c1g, cw2, cb2, cw3, out + N,
                                                   P, gbias, aw2, ab2, out, N);
}